// Round 6
// baseline (902.834 us; speedup 1.0000x reference)
//
#include <hip/hip_runtime.h>
#include <math.h>

namespace {

constexpr int kL  = 1024;
constexpr int kD  = 1024;
constexpr int kB  = 4;
constexpr int kH  = 16;
constexpr int kDK = 64;
constexpr int kHID = 4096;

typedef unsigned short ushort_t;
typedef short  s16x8 __attribute__((ext_vector_type(8)));   // 8 bf16 (4 VGPRs) MFMA frag
typedef float  f32x4 __attribute__((ext_vector_type(4)));
typedef unsigned short u16x4 __attribute__((ext_vector_type(4)));

// fp32 -> bf16 round-to-nearest-even
__device__ __forceinline__ ushort_t f2bf(float f) {
    unsigned u = __float_as_uint(f);
    unsigned r = u + 0x7fffu + ((u >> 16) & 1u);
    return (ushort_t)(r >> 16);
}

// async global->LDS, 16B per lane. LDS dest = wave-uniform base + lane*16.
__device__ __forceinline__ void gld16(const void* g, void* l) {
    __builtin_amdgcn_global_load_lds((__attribute__((address_space(1))) void*)(g),
                                     (__attribute__((address_space(3))) void*)(l),
                                     16, 0, 0);
}

__device__ __forceinline__ float wred_sum(float v) {
    #pragma unroll
    for (int o = 32; o > 0; o >>= 1) v += __shfl_xor(v, o, 64);
    return v;
}

// ---------------------------------------------------------------------------
// prep: all input-independent prologue work in ONE launch.
// ---------------------------------------------------------------------------
__global__ __launch_bounds__(256) void prep(
    const float* __restrict__ wq_w, const float* __restrict__ wk_w,
    const float* __restrict__ wv_w, const float* __restrict__ fc_w,
    ushort_t* __restrict__ wT4,
    const float* __restrict__ mlp1_w, ushort_t* __restrict__ m1T,
    const float* __restrict__ mlp2_w, ushort_t* __restrict__ m2T,
    const float* __restrict__ kx, const float* __restrict__ vx, ushort_t* __restrict__ kv,
    const float* __restrict__ q, const float* __restrict__ z,
    const float* __restrict__ ln1w, const float* __restrict__ ln1b,
    const float* __restrict__ g1, const float* __restrict__ b1,
    float* __restrict__ qp, ushort_t* __restrict__ qb)
{
    __shared__ float t[32][33];
    __shared__ float r1[4], r2[4];
    const int b = blockIdx.x;
    const int tid = threadIdx.x;
    if (b < 12288) {
        const float* src; ushort_t* dst; int R, C, bx, by;
        if (b < 4096) {
            int zz = b >> 10, idx = b & 1023;
            src = zz == 0 ? wq_w : zz == 1 ? wk_w : zz == 2 ? wv_w : fc_w;
            dst = wT4 + (size_t)zz * 1048576;
            R = 1024; C = 1024; bx = idx & 31; by = idx >> 5;
        } else if (b < 8192) {
            int idx = b - 4096;
            src = mlp1_w; dst = m1T; R = 1024; C = 4096;
            bx = idx & 127; by = idx >> 7;
        } else {
            int idx = b - 8192;
            src = mlp2_w; dst = m2T; R = 4096; C = 1024;
            bx = idx & 31; by = idx >> 5;
        }
        int c0 = bx * 32, rr0 = by * 32;
        int tx = tid & 31, ty = tid >> 5;
        #pragma unroll
        for (int i = 0; i < 4; i++) {
            int r = ty + i * 8;
            t[r][tx] = src[(size_t)(rr0 + r) * C + c0 + tx];
        }
        __syncthreads();
        #pragma unroll
        for (int i = 0; i < 4; i++) {
            int c = ty + i * 8;
            dst[(size_t)(c0 + c) * R + rr0 + tx] = f2bf(t[tx][c]);
        }
        return;
    }
    if (b < 20480) {
        int bb = b - 12288;
        bool isv = bb >= 4096;
        const float* src = isv ? vx : kx;
        ushort_t* dst = kv + (isv ? (size_t)4194304 : 0);
        int i = (bb & 4095) * 256 + tid;
        f32x4 v = ((const f32x4*)src)[i];
        u16x4 o; o[0] = f2bf(v[0]); o[1] = f2bf(v[1]); o[2] = f2bf(v[2]); o[3] = f2bf(v[3]);
        ((u16x4*)dst)[i] = o;
        return;
    }
    // sln1 row
    {
        const int row = b - 20480;
        const size_t base = (size_t)row * kD;
        float4 xv = ((const float4*)(q + base))[tid];
        float s  = xv.x + xv.y + xv.z + xv.w;
        float sq = xv.x * xv.x + xv.y * xv.y + xv.z * xv.z + xv.w * xv.w;
        float ws = wred_sum(s), wq = wred_sum(sq);
        int lane = tid & 63, wid = tid >> 6;
        if (lane == 0) { r1[wid] = ws; r2[wid] = wq; }
        __syncthreads();
        float st = r1[0] + r1[1] + r1[2] + r1[3];
        float qt = r2[0] + r2[1] + r2[2] + r2[3];
        float mean = st * (1.0f / kD);
        float var  = qt * (1.0f / kD) - mean * mean;
        float rs = rsqrtf(var + 1e-5f);
        float gv = g1[0], bv = b1[0];
        float4 zv = ((const float4*)(z + base))[tid];
        float4 wv = ((const float4*)ln1w)[tid];
        float4 lb = ((const float4*)ln1b)[tid];
        float4 o;
        o.x = zv.x * (gv * ((xv.x - mean) * rs * wv.x + lb.x) + bv);
        o.y = zv.y * (gv * ((xv.y - mean) * rs * wv.y + lb.y) + bv);
        o.z = zv.z * (gv * ((xv.z - mean) * rs * wv.z + lb.z) + bv);
        o.w = zv.w * (gv * ((xv.w - mean) * rs * wv.w + lb.w) + bv);
        ((float4*)(qp + base))[tid] = o;
        u16x4 ob; ob[0] = f2bf(o.x); ob[1] = f2bf(o.y); ob[2] = f2bf(o.z); ob[3] = f2bf(o.w);
        ((u16x4*)(qb + base))[tid] = ob;
    }
}

// out = z * (g * LN(x) + b), where x = x1 (+ x2 partial).
__global__ __launch_bounds__(256) void sln_kernel(
    const float* __restrict__ x, const float* __restrict__ x2, float* __restrict__ xw,
    const float* __restrict__ z,
    const float* __restrict__ lnw, const float* __restrict__ lnb,
    const float* __restrict__ g, const float* __restrict__ bt,
    float* __restrict__ outf, ushort_t* __restrict__ outb)
{
    const int row = blockIdx.x;
    const int tid = threadIdx.x;
    const size_t base = (size_t)row * kD;
    float4 xv = ((const float4*)(x + base))[tid];
    if (x2) {
        float4 a = ((const float4*)(x2 + base))[tid];
        xv.x += a.x; xv.y += a.y; xv.z += a.z; xv.w += a.w;
    }
    if (xw) ((float4*)(xw + base))[tid] = xv;
    float s  = xv.x + xv.y + xv.z + xv.w;
    float sq = xv.x * xv.x + xv.y * xv.y + xv.z * xv.z + xv.w * xv.w;
    __shared__ float r1[4], r2[4];
    float ws = wred_sum(s), wq = wred_sum(sq);
    int lane = tid & 63, wid = tid >> 6;
    if (lane == 0) { r1[wid] = ws; r2[wid] = wq; }
    __syncthreads();
    float st = r1[0] + r1[1] + r1[2] + r1[3];
    float qt = r2[0] + r2[1] + r2[2] + r2[3];
    float mean = st * (1.0f / kD);
    float var  = qt * (1.0f / kD) - mean * mean;
    float rs = rsqrtf(var + 1e-5f);
    float gv = g[0], bv = bt[0];
    float4 zv = ((const float4*)(z + base))[tid];
    float4 wv = ((const float4*)lnw)[tid];
    float4 lb = ((const float4*)lnb)[tid];
    float4 o;
    o.x = zv.x * (gv * ((xv.x - mean) * rs * wv.x + lb.x) + bv);
    o.y = zv.y * (gv * ((xv.y - mean) * rs * wv.y + lb.y) + bv);
    o.z = zv.z * (gv * ((xv.z - mean) * rs * wv.z + lb.z) + bv);
    o.w = zv.w * (gv * ((xv.w - mean) * rs * wv.w + lb.w) + bv);
    if (outf) ((float4*)(outf + base))[tid] = o;
    u16x4 ob; ob[0] = f2bf(o.x); ob[1] = f2bf(o.y); ob[2] = f2bf(o.z); ob[3] = f2bf(o.w);
    ((u16x4*)(outb + base))[tid] = ob;
}

// dst += p1 + p2 + p3 (fp32)
__global__ __launch_bounds__(256) void combine4(
    float* __restrict__ dst, const float* __restrict__ p1,
    const float* __restrict__ p2, const float* __restrict__ p3)
{
    int i = blockIdx.x * 256 + threadIdx.x;
    f32x4 d = ((const f32x4*)dst)[i];
    f32x4 a = ((const f32x4*)p1)[i];
    f32x4 b = ((const f32x4*)p2)[i];
    f32x4 c = ((const f32x4*)p3)[i];
    d[0] += a[0] + b[0] + c[0]; d[1] += a[1] + b[1] + c[1];
    d[2] += a[2] + b[2] + c[2]; d[3] += a[3] + b[3] + c[3];
    ((f32x4*)dst)[i] = d;
}

// vh bf16 [b][j][h*64+d] -> vhT bf16 [p=h*4+b][d][j]
__global__ __launch_bounds__(256) void vtrans(
    const ushort_t* __restrict__ vh, ushort_t* __restrict__ vhT)
{
    __shared__ ushort_t t[32][33];
    int p = blockIdx.z, b = p & 3, h = p >> 2;
    int j0 = blockIdx.x * 32, d0 = blockIdx.y * 32;
    int tx = threadIdx.x & 31, ty = threadIdx.x >> 5;
    const ushort_t* src = vh + (size_t)b * (kL * kD) + h * kDK;
    #pragma unroll
    for (int i = 0; i < 4; i++) {
        int j = ty + i * 8;
        t[j][tx] = src[(size_t)(j0 + j) * kD + d0 + tx];
    }
    __syncthreads();
    ushort_t* dst = vhT + (size_t)p * (kDK * kL);
    #pragma unroll
    for (int i = 0; i < 4; i++) {
        int d = ty + i * 8;
        dst[(size_t)(d0 + d) * kL + j0 + tx] = t[tx][d];
    }
}

// MFMA GEMM (m97 structure): used for fc (split-K x2, mode 3).
__global__ __launch_bounds__(256) void mgemm(
    const ushort_t* __restrict__ A, int lda,
    const ushort_t* __restrict__ Bt, int ldb,
    void* __restrict__ Cv, int ldc, int K,
    const float* __restrict__ bias, const float* __restrict__ res,
    float scale, int flags, int mode,
    const float* __restrict__ bias1, void* __restrict__ Cv2)
{
    __shared__ __align__(16) ushort_t As[128 * 32];
    __shared__ __align__(16) ushort_t Bs[128 * 32];
    if (mode == 3) {
        int zz = blockIdx.z;
        A  += (size_t)zz * K;
        Bt += (size_t)zz * K;
        if (zz == 1) { Cv = Cv2; bias = nullptr; res = nullptr; flags = 0; }
    }
    float*    Cf = (float*)Cv;
    ushort_t* Cb = (ushort_t*)Cv;
    const int nx = gridDim.x, nwg = nx * gridDim.y;
    int f = blockIdx.y * nx + blockIdx.x;
    int rr = (f & 7) * (nwg >> 3) + (f >> 3);
    const int bx = rr % nx, by = rr / nx;
    const int tid = threadIdx.x;
    const int lane = tid & 63, w = tid >> 6;
    const int m0 = by * 128, n0 = bx * 128;
    const int r0 = tid >> 2;
    const int c0 = (tid & 3) ^ (r0 & 3);
    const ushort_t* Ag0 = A  + (size_t)(m0 + r0) * lda + c0 * 8;
    const ushort_t* Ag1 = Ag0 + (size_t)64 * lda;
    const ushort_t* Bg0 = Bt + (size_t)(n0 + r0) * ldb + c0 * 8;
    const ushort_t* Bg1 = Bg0 + (size_t)64 * ldb;
    char* AsW = (char*)As + w * 1024;
    char* BsW = (char*)Bs + w * 1024;
    const int wm = (w & 1) * 64, wn = (w >> 1) * 64;
    const int fn = lane & 15, q = lane >> 4;
    int aoff[4], boff[4];
    #pragma unroll
    for (int i = 0; i < 4; i++) {
        int ra = wm + i * 16 + fn;
        aoff[i] = (ra * 4 + (q ^ (ra & 3))) * 16;
        int rb = wn + i * 16 + fn;
        boff[i] = (rb * 4 + (q ^ (rb & 3))) * 16;
    }
    f32x4 acc[4][4] = {};
    for (int k0 = 0; k0 < K; k0 += 32) {
        gld16(Ag0 + k0, AsW);
        gld16(Ag1 + k0, AsW + 4096);
        gld16(Bg0 + k0, BsW);
        gld16(Bg1 + k0, BsW + 4096);
        __syncthreads();
        s16x8 af[4], bfr[4];
        #pragma unroll
        for (int i = 0; i < 4; i++) {
            af[i]  = *(const s16x8*)((const char*)As + aoff[i]);
            bfr[i] = *(const s16x8*)((const char*)Bs + boff[i]);
        }
        #pragma unroll
        for (int mi = 0; mi < 4; mi++)
            #pragma unroll
            for (int ni = 0; ni < 4; ni++)
                acc[mi][ni] = __builtin_amdgcn_mfma_f32_16x16x32_bf16(
                    af[mi], bfr[ni], acc[mi][ni], 0, 0, 0);
        __syncthreads();
    }
    #pragma unroll
    for (int mi = 0; mi < 4; mi++) {
        #pragma unroll
        for (int ni = 0; ni < 4; ni++) {
            #pragma unroll
            for (int r = 0; r < 4; r++) {
                int gm = m0 + wm + mi * 16 + q * 4 + r;
                int gn = n0 + wn + ni * 16 + fn;
                float v = acc[mi][ni][r] * scale;
                if (bias) v += bias[gn];
                if (flags & 1) v = 0.5f * v * (1.0f + erff(v * 0.70710678118654752f));
                if (res) v += res[(size_t)gm * ldc + gn];
                if (flags & 2) Cb[(size_t)gm * ldc + gn] = f2bf(v);
                else           Cf[(size_t)gm * ldc + gn] = v;
            }
        }
    }
}

// ---------------------------------------------------------------------------
// g8: 8-phase deep-pipelined GEMM (m201/m248 template, plain HIP).
// 256x256 tile, BK=64, 8 waves (2Mx4N), LDS = 2 dbuf x (A 32K + B 32K) = 128K.
// Halves by fragment group: A.h0 = af[0-3] rows {0-63,128-191}, A.h1 = af[4-7]
// rows {64-127,192-255}; B.h0 = bf[0-1] rows (r&63)<32, B.h1 = bf[2-3].
// Each half is ds_read in exactly ONE phase -> per-phase 1-half-tile staging is
// write-after-read safe (stage issued >=1 phase after the half's read; two
// barriers + lgkmcnt(0) in between make the read architecturally complete).
// Stage schedule ph1..8: {t1.A1, t2.A0, t2.B0, t2.B1, t2.A1, t3.A0, t3.B0,
// t3.B1}; counted vmcnt(6) ONLY at ph4/ph8 (3 half-tiles in flight).
// XOR chunk swizzle c^(r&7) on 128B rows via pre-swizzled global source.
// flags: 1=gelu, 2=bf16 out. mode 2 = QKV z-batch. mode 4 = split-K x4.
// ---------------------------------------------------------------------------
#define G8_PRE()  do { __builtin_amdgcn_sched_barrier(0); __builtin_amdgcn_s_barrier(); \
    asm volatile("s_waitcnt lgkmcnt(0)" ::: "memory"); \
    __builtin_amdgcn_sched_barrier(0); __builtin_amdgcn_s_setprio(1); } while (0)
#define G8_POST() do { __builtin_amdgcn_s_setprio(0); __builtin_amdgcn_sched_barrier(0); \
    __builtin_amdgcn_s_barrier(); } while (0)
#define STG_A(T, h, base) do { \
    const ushort_t* _s = Aga + (size_t)(T) * 64 + (size_t)((h) * 64) * lda; \
    gld16(_s, (base) + (h) * 16384 + sdst); \
    gld16(_s + (size_t)128 * lda, (base) + (h) * 16384 + 8192 + sdst); } while (0)
#define STG_B(T, h, base) do { \
    const ushort_t* _s = Bga + (size_t)(T) * 64 + (size_t)((h) * 32) * ldb; \
    gld16(_s, (base) + (h) * 16384 + sdst); \
    gld16(_s + (size_t)128 * ldb, (base) + (h) * 16384 + 8192 + sdst); } while (0)
#define RD_A(base, half) do { _Pragma("unroll") \
    for (int i = 0; i < 4; i++) { \
        af[i][0] = *(const s16x8*)((base) + (half) * 16384 + aoff[i] + xoff0); \
        af[i][1] = *(const s16x8*)((base) + (half) * 16384 + aoff[i] + xoff1); } } while (0)
#define RD_B(dst, base, half) do { _Pragma("unroll") \
    for (int j = 0; j < 2; j++) { \
        dst[j][0] = *(const s16x8*)((base) + (half) * 16384 + boff[j] + xoff0); \
        dst[j][1] = *(const s16x8*)((base) + (half) * 16384 + boff[j] + xoff1); } } while (0)
#define QUAD(MB, NB, BF) do { _Pragma("unroll") \
    for (int ks = 0; ks < 2; ks++) { _Pragma("unroll") \
        for (int mi = 0; mi < 4; mi++) { _Pragma("unroll") \
            for (int ni = 0; ni < 2; ni++) \
                acc[(MB) + mi][(NB) + ni] = __builtin_amdgcn_mfma_f32_16x16x32_bf16( \
                    af[mi][ks], BF[ni][ks], acc[(MB) + mi][(NB) + ni], 0, 0, 0); } } } while (0)

__global__ __launch_bounds__(512, 1) void g8(
    const ushort_t* __restrict__ A, int lda,
    const ushort_t* __restrict__ Bt, int ldb,
    void* __restrict__ Cv, int ldc, int K,
    const float* __restrict__ bias, const float* __restrict__ res,
    int flags, int mode,
    const float* __restrict__ bias1, const float* __restrict__ bias2,
    float* __restrict__ Cp1, float* __restrict__ Cp2, float* __restrict__ Cp3)
{
    __shared__ __align__(16) char lds[131072];
    if (mode == 2) {
        int zz = blockIdx.z;
        A  += (size_t)zz * 4194304u;     // qb,kb,vb at 8MB spacing
        Bt += (size_t)zz * 1048576u;     // wqT,wkT,wvT at 2MB spacing
        Cv = (void*)((ushort_t*)Cv + (size_t)zz * 4194304u);
        if (zz == 1) bias = bias1;
        else if (zz == 2) bias = bias2;
    } else if (mode == 4) {
        int zz = blockIdx.z;
        A  += (size_t)zz * K;
        Bt += (size_t)zz * K;
        if (zz > 0) {
            Cv = (void*)(zz == 1 ? Cp1 : zz == 2 ? Cp2 : Cp3);
            bias = nullptr; res = nullptr; flags = 0;
        }
    }
    float*    Cf = (float*)Cv;
    ushort_t* Cb = (ushort_t*)Cv;
    // XCD-bijective swizzle (nwg%8==0 for all grids used)
    const int nx = gridDim.x, nwg = nx * gridDim.y;
    int f = blockIdx.y * nx + blockIdx.x;
    int rr = (f & 7) * (nwg >> 3) + (f >> 3);
    const int bx = rr % nx, by = rr / nx;
    const int tid = threadIdx.x;
    const int lane = tid & 63, w = tid >> 6;
    const int wr = w >> 2, wc = w & 3;          // wave tile 128M x 64N
    const int fn = lane & 15, q = lane >> 4;
    const int m0 = by * 256, n0 = bx * 256;
    // staging addressing: lane covers row-in-issue ar, source chunk cb
    const int ar = w * 8 + (lane >> 3);
    const int cb = ((lane & 7) ^ ((lane >> 3) & 7)) * 8;
    const int br0 = ((ar >> 5) << 6) + (ar & 31);
    const ushort_t* Aga = A  + (size_t)(m0 + ar)  * lda + cb;
    const ushort_t* Bga = Bt + (size_t)(n0 + br0) * ldb + cb;
    const int sdst = w * 1024;
    char* const Ab0 = lds;
    char* const Bb0 = lds + 32768;
    char* const Ab1 = lds + 65536;
    char* const Bb1 = lds + 98304;
    // fragment read offsets (within a 16KB half region; rows 128B, xor-swizzled)
    const int xoff0 = ((q)     ^ (fn & 7)) << 4;
    const int xoff1 = ((4 + q) ^ (fn & 7)) << 4;
    int aoff[4], boff[2];
    #pragma unroll
    for (int i = 0; i < 4; i++) aoff[i] = ((i << 4) + fn + wr * 64) * 128;
    #pragma unroll
    for (int j = 0; j < 2; j++) boff[j] = ((j << 4) + fn + wc * 32) * 128;

    const int NT = K >> 6;
    f32x4 acc[8][4] = {};
    s16x8 af[4][2], bf01[2][2], bf23[2][2];

    // prologue: tile0 fully into buf0 (8 issues), tile1 A.h0,B.h0,B.h1 (6)
    STG_A(0, 0, Ab0); STG_A(0, 1, Ab0); STG_B(0, 0, Bb0); STG_B(0, 1, Bb0);
    STG_A(1, 0, Ab1); STG_B(1, 0, Bb1); STG_B(1, 1, Bb1);
    asm volatile("s_waitcnt vmcnt(6)" ::: "memory");   // tile0 landed
    __builtin_amdgcn_s_barrier();
    __builtin_amdgcn_sched_barrier(0);

    for (int it = 0; it < (NT >> 1); ++it) {
        const int t0 = it << 1, t1 = t0 | 1;
        const bool s2 = (t0 + 2) < NT;     // implies s3 below when true
        const bool s3 = (t0 + 3) < NT;
        // ph1: read buf0 {A.h0, B.h0}; stage t1.A.h1 -> buf1
        STG_A(t1, 1, Ab1);
        RD_A(Ab0, 0); RD_B(bf01, Bb0, 0);
        G8_PRE(); QUAD(0, 0, bf01); G8_POST();
        // ph2: read buf0 B.h1; stage t2.A.h0 -> buf0
        if (s2) STG_A(t0 + 2, 0, Ab0);
        RD_B(bf23, Bb0, 1);
        G8_PRE(); QUAD(0, 2, bf23); G8_POST();
        // ph3: read buf0 A.h1; stage t2.B.h0
        if (s2) STG_B(t0 + 2, 0, Bb0);
        RD_A(Ab0, 1);
        G8_PRE(); QUAD(4, 0, bf01); G8_POST();
        // ph4: stage t2.B.h1; counted vmcnt -> t1 fully landed
        if (s2) STG_B(t0 + 2, 1, Bb0);
        if (s2) asm volatile("s_waitcnt vmcnt(6)" ::: "memory");
        else    asm volatile("s_waitcnt vmcnt(0)" ::: "memory");
        G8_PRE(); QUAD(4, 2, bf23); G8_POST();
        // ph5: read buf1 {A.h0, B.h0}; stage t2.A.h1 -> buf0
        if (s2) STG_A(t0 + 2, 1, Ab0);
        RD_A(Ab1, 0); RD_B(bf01, Bb1, 0);
        G8_PRE(); QUAD(0, 0, bf01); G8_POST();
        // ph6: read buf1 B.h1; stage t3.A.h0 -> buf1
        if (s3) STG_A(t0 + 3, 0, Ab1);
        RD_B(bf23, Bb1, 1);
        G8_PRE(); QUAD(0, 2, bf23); G8_POST();
        // ph7: read buf1 A.h1; stage t3.B.h0
        if (s3) STG_B(t0 + 3, 0, Bb1);
        RD_A(Ab1, 1);
        G8_PRE(); QUAD(4, 0, bf01); G8_POST();
        // ph8: stage t3.B.h1; counted vmcnt -> t2 fully landed
        if (s3) STG_B(t0 + 3, 1, Bb1);
        if (s3) asm volatile("s_waitcnt vmcnt(6)" ::: "memory");
        else    asm volatile("s_waitcnt vmcnt(0)" ::: "memory");
        G8_PRE(); QUAD(4, 2, bf23); G8_POST();
    }

    #pragma unroll
    for (int mi = 0; mi < 8; mi++) {
        #pragma unroll
        for (int ni = 0; ni < 4; ni++) {
            #pragma unroll
            for (int r = 0; r < 4; r++) {
                int gm = m0 + wr * 128 + mi * 16 + q * 4 + r;
                int gn = n0 + wc * 64 + ni * 16 + fn;
                float v = acc[mi][ni][r];
                if (bias) v += bias[gn];
                if (flags & 1) v = 0.5f * v * (1.0f + erff(v * 0.70710678118654752f));
                if (res) v += res[(size_t)gm * ldc + gn];
                if (flags & 2) Cb[(size_t)gm * ldc + gn] = f2bf(v);
                else           Cf[(size_t)gm * ldc + gn] = v;
            }
        }
    }
}

// Fused attention (R3 version): per block = one (b,h) pair p, 32-row Q-tile.
__global__ __launch_bounds__(512) void fused_attn(
    const ushort_t* __restrict__ qh, const ushort_t* __restrict__ kh,
    const ushort_t* __restrict__ vhT, float* __restrict__ attn,
    ushort_t* __restrict__ ctx)
{
    __shared__ __align__(16) char PlBuf[8 * 4096];
    __shared__ float redm[8][32];
    __shared__ float reds[8][32];
    const int orig = blockIdx.y * 32 + blockIdx.x;
    const int nf = (orig & 7) * 256 + (orig >> 3);
    const int p = nf >> 5, b = p & 3, h = p >> 2;
    const int m0 = (nf & 31) * 32;
    const int tid = threadIdx.x;
    const int lane = tid & 63, w = tid >> 6;
    const int fn = lane & 15, q = lane >> 4;
    const ushort_t* Qb = qh + (size_t)b * (kL * kD) + h * 64;
    const ushort_t* Kb = kh + (size_t)b * (kL * kD) + h * 64;
    float* Pp = attn + (size_t)p * kL * kL;

    f32x4 acc[2][8] = {};
    #pragma unroll
    for (int kk = 0; kk < 2; kk++) {
        s16x8 aq[2], bq[8];
        #pragma unroll
        for (int mi = 0; mi < 2; mi++)
            aq[mi] = *(const s16x8*)(Qb + (size_t)(m0 + mi * 16 + fn) * kD + kk * 32 + q * 8);
        #pragma unroll
        for (int ni = 0; ni < 8; ni++)
            bq[ni] = *(const s16x8*)(Kb + (size_t)(w * 128 + ni * 16 + fn) * kD + kk * 32 + q * 8);
        #pragma unroll
        for (int mi = 0; mi < 2; mi++)
            #pragma unroll
            for (int ni = 0; ni < 8; ni++)
                acc[mi][ni] = __builtin_amdgcn_mfma_f32_16x16x32_bf16(
                    aq[mi], bq[ni], acc[mi][ni], 0, 0, 0);
    }

    float mloc[2][4];
    #pragma unroll
    for (int mi = 0; mi < 2; mi++) {
        #pragma unroll
        for (int r = 0; r < 4; r++) {
            float m = -3.0e38f;
            #pragma unroll
            for (int ni = 0; ni < 8; ni++) {
                acc[mi][ni][r] *= 0.125f;
                m = fmaxf(m, acc[mi][ni][r]);
            }
            mloc[mi][r] = m;
        }
    }
    #pragma unroll
    for (int o = 1; o < 16; o <<= 1) {
        #pragma unroll
        for (int mi = 0; mi < 2; mi++)
            #pragma unroll
            for (int r = 0; r < 4; r++)
                mloc[mi][r] = fmaxf(mloc[mi][r], __shfl_xor(mloc[mi][r], o, 64));
    }
    if (fn == 0) {
        #pragma unroll
        for (int mi = 0; mi < 2; mi++)
            #pragma unroll
            for (int r = 0; r < 4; r++)
                redm[w][mi * 16 + q * 4 + r] = mloc[mi][r];
    }
    __syncthreads();
    #pragma unroll
    for (int mi = 0; mi < 2; mi++) {
        #pragma unroll
        for (int r = 0; r < 4; r++) {
            int row = mi * 16 + q * 4 + r;
            float m = redm[0][row];
            #pragma unroll
            for (int w2 = 1; w2 < 8; w2++) m = fmaxf(m, redm[w2][row]);
            float s = 0.f;
            #pragma unroll
            for (int ni = 0; ni < 8; ni++) {
                float e = __expf(acc[mi][ni][r] - m);
                acc[mi][ni][r] = e;
                s += e;
            }
            mloc[mi][r] = s;
        }
    }
    #pragma unroll
    for (int o = 1; o < 16; o <<= 1) {
        #pragma unroll
        for (int mi = 0; mi < 2; mi++)
            #pragma unroll
            for (int r = 0; r < 4; r++)
                mloc[mi][r] += __shfl_xor(mloc[mi][r], o, 64);
    }
    if (fn == 0) {
        #pragma unroll
        for (int mi = 0; mi < 2; mi++)
            #pragma unroll
            for (int r = 0; r < 4; r++)
                reds[w][mi * 16 + q * 4 + r] = mloc[mi][r];
    }
    __syncthreads();
    float inv[2][4];
    #pragma unroll
    for (int mi = 0; mi < 2; mi++) {
        #pragma unroll
        for (int r = 0; r < 4; r++) {
            int row = mi * 16 + q * 4 + r;
            float s = reds[0][row];
            #pragma unroll
            for (int w2 = 1; w2 < 8; w2++) s += reds[w2][row];
            inv[mi][r] = 1.0f / s;
        }
    }
    #pragma unroll
    for (int mi = 0; mi < 2; mi++)
        #pragma unroll
        for (int ni = 0; ni < 8; ni++)
            #pragma unroll
            for (int r = 0; r < 4; r++)
                __builtin_nontemporal_store(
                    acc[mi][ni][r] * inv[mi][r],
                    &Pp[(size_t)(m0 + mi * 16 + q * 4 + r) * kL + w * 128 + ni * 16 + fn]);

    const ushort_t* Vb = vhT + (size_t)p * (kDK * kL);
    char* Plw = PlBuf + w * 4096;
    f32x4 acc2[2][4] = {};
    #pragma unroll
    for (int half = 0; half < 2; half++) {
        #pragma unroll
        for (int mi = 0; mi < 2; mi++)
            #pragma unroll
            for (int ni = 0; ni < 4; ni++)
                #pragma unroll
                for (int r = 0; r < 4; r++) {
                    int row = mi * 16 + q * 4 + r;
                    int cl  = ni * 16 + fn;
                    *(ushort_t*)(Plw + ((row * 128 + cl * 2) ^ ((row & 7) << 4)))
                        = f2bf(acc[mi][half * 4 + ni][r]);
                }
        #pragma unroll
        for (int kh2 = 0; kh2 < 2; kh2++) {
            int kk = half * 2 + kh2;
            s16x8 pa[2];
            #pragma unroll
            for (int mi = 0; mi < 2; mi++) {
                int row = mi * 16 + fn;
                pa[mi] = *(const s16x8*)(Plw +
                    ((row * 128 + (kh2 * 32 + q * 8) * 2) ^ ((row & 7) << 4)));
            }
            #pragma unroll
            for (int nj = 0; nj < 4; nj++) {
                s16x8 bv = *(const s16x8*)(Vb + (size_t)(nj * 16 + fn) * kL +
                                           w * 128 + kk * 32 + q * 8);
                #pragma unroll
                for (int mi = 0; mi < 2; mi++)
                    acc2[mi][nj] = __builtin_amdgcn_mfma_f32_16x16x32_bf16(
                        pa[mi], bv, acc2[mi][nj], 0, 0, 0);
            }
        }
    }
    #pragma unroll
    for (int mi = 0; mi < 2; mi++)
        #pragma unroll
        for (int nj = 0; nj < 4; nj++)
            #pragma unroll
            for (int r = 0; r < 4; r++)
                acc2[mi][nj][r] *= inv[mi][r];

    __syncthreads();
    float (*cred)[2048] = (float (*)[2048])PlBuf;
    if (w < 4) {
        #pragma unroll
        for (int mi = 0; mi < 2; mi++)
            #pragma unroll
            for (int nj = 0; nj < 4; nj++)
                #pragma unroll
                for (int r = 0; r < 4; r++)
                    cred[w][(mi * 16 + q * 4 + r) * 64 + nj * 16 + fn] = acc2[mi][nj][r];
    }
    __syncthreads();
    if (w >= 4) {
        #pragma unroll
        for (int mi = 0; mi < 2; mi++)
            #pragma unroll
            for (int nj = 0; nj < 4; nj++)
                #pragma unroll
                for (int r = 0; r < 4; r++)
                    cred[w - 4][(mi * 16 + q * 4 + r) * 64 + nj * 16 + fn] += acc2[mi][nj][r];
    }
    __syncthreads();
    {
        int idx0 = tid * 4;
        int row = idx0 >> 6, d0 = idx0 & 63;
        f32x4 s0 = *(const f32x4*)&cred[0][idx0];
        #pragma unroll
        for (int wb = 1; wb < 4; wb++) {
            f32x4 t = *(const f32x4*)&cred[wb][idx0];
            s0[0] += t[0]; s0[1] += t[1]; s0[2] += t[2]; s0[3] += t[3];
        }
        u16x4 o;
        o[0] = f2bf(s0[0]); o[1] = f2bf(s0[1]); o[2] = f2bf(s0[2]); o[3] = f2bf(s0[3]);
        *(u16x4*)(ctx + (size_t)b * (kL * kD) + (size_t)(m0 + row) * kD + h * 64 + d0) = o;
    }
}

} // namespace

extern "C" void kernel_launch(void* const* d_in, const int* in_sizes, int n_in,
                              void* d_out, int out_size, void* d_ws, size_t ws_size,
                              hipStream_t stream)
{
    (void)in_sizes; (void)n_in; (void)out_size; (void)ws_size;
    const float* q      = (const float*)d_in[0];
    const float* k      = (const float*)d_in[1];
    const float* v      = (const float*)d_in[2];
    const float* z      = (const float*)d_in[3];
    const float* wq_w   = (const float*)d_in[4];
    const float* wq_b   = (const float*)d_in[5];
    const float* wk_w   = (const float*)d_in[6];
    const float* wk_b   = (const float*)d_in[7];
    const float* wv_w   = (const float*)d_in[8];
    const float* wv_b   = (const float*)d_in[9];
    const float* fc_w   = (const float*)d_in[10];
    const float* fc_b   = (const float*)d_in[11];
    const float* mlp1_w = (const float*)d_in[12];
    const float* mlp1_b = (const float*)d_in[13];
    const float* mlp2_w = (const float*)d_in[14];
    const float* mlp2_b = (const float*)d_in[15];
    const float* ln1_w  = (const float*)d_in[16];
    const float* ln1_b  = (const float*)d_in[17];
    const float* g1     = (const float*)d_in[18];
    const float* b1     = (const float*)d_in[19];
    const float* ln2_w  = (const float*)d_in[20];
    const float* ln2_b  = (const float*)d_in[21];
    const float* g2     = (const float*)d_in[22];
    const float* b2     = (const float*)d_in[23];

    float* out0 = (float*)d_out;                          // (B,L,D)
    float* attn = (float*)d_out + (size_t)kB * kL * kD;   // (H*B,L,L)

    // arena (104 MB, lifetime overlays):
    //  [0,16)  qp -> hid [0,32) at mlp1
    //  [16,24) qb [24,32) kb -> fcP [16,32) at fc
    //  [32,40) vb -> vhT (after QKV) -> h2 (after attn) -> p1 [32,48) at mlp2
    //  [40,48) qh -> dead after attn
    //  [48,56) kh -> p2 [48,64) at mlp2
    //  [56,64) vh -> ctx (after vtrans) -> dead after fc
    //  [64,80) out1
    //  [80,104) wT4(8MB: wq,wk,wv,fc), m1T [88,96), m2T [96,104); p3 [80,96) at mlp2
    char* arena = (char*)d_ws;
    const size_t MB = 1u << 20;
    float*    qp   = (float*)(arena);
    ushort_t* qb   = (ushort_t*)(arena + 16 * MB);
    ushort_t* kb   = (ushort_t*)(arena + 24 * MB);
    ushort_t* vb   = (ushort_t*)(arena + 32 * MB);
    ushort_t* qh   = (ushort_t*)(arena + 40 * MB);
    ushort_t* kh   = (ushort_t*)(arena + 48 * MB);
    ushort_t* vh   = (ushort_t*)(arena + 56 * MB);
    ushort_t* vhT  = (ushort_t*)(arena + 32 * MB);     // overlays vb (dead)
    ushort_t* ctx  = (ushort_t*)(arena + 56 * MB);     // overlays vh (dead)
    float*    fcP  = (float*)(arena + 16 * MB);        // overlays qb,kb (dead)
    ushort_t* h2   = (ushort_t*)(arena + 32 * MB);     // overlays vhT (dead)
    float*    out1 = (float*)(arena + 64 * MB);
    ushort_t* hid  = (ushort_t*)(arena);               // [0,32) overlays qp,fcP (dead)
    float*    p1   = (float*)(arena + 32 * MB);        // mlp2 partials
    float*    p2   = (float*)(arena + 48 * MB);
    float*    p3   = (float*)(arena + 80 * MB);        // weights wT4..m1T dead
    ushort_t* wT4  = (ushort_t*)(arena + 80 * MB);
    ushort_t* fcT  = (ushort_t*)(arena + 86 * MB);
    ushort_t* m1T  = (ushort_t*)(arena + 88 * MB);
    ushort_t* m2T  = (ushort_t*)(arena + 96 * MB);

    dim3 blk(256);
    // 0) all prologue work in one launch
    prep<<<dim3(24576), blk, 0, stream>>>(wq_w, wk_w, wv_w, fc_w, wT4,
                                          mlp1_w, m1T, mlp2_w, m2T,
                                          k, v, kb,
                                          q, z, ln1_w, ln1_b, g1, b1, qp, qb);
    // 1) QKV projections, 8-phase 256^2, z-batched (192 blocks)
    g8<<<dim3(4, 16, 3), dim3(512), 0, stream>>>(qb, kD, wT4, kD, qh, kD, kD,
                                                 wq_b, nullptr, 2, 2, wk_b, wv_b,
                                                 nullptr, nullptr, nullptr);
    // 2) V^T per head
    vtrans<<<dim3(32, 2, 64), blk, 0, stream>>>(vh, vhT);
    // 3) fused scores+softmax+PV
    fused_attn<<<dim3(kL / 32, 64), dim3(512), 0, stream>>>(qh, kh, vhT, attn, ctx);
    // 4) out1 = ctx @ fc_w + fc_b + q', m97 split-K x2 (512 blocks)
    mgemm<<<dim3(8, 32, 2), blk, 0, stream>>>(ctx, kD, fcT, kD, out1, kD, kD / 2,
                                              fc_b, qp, 1.0f, 0, 3, nullptr, fcP);
    // 5) h2 = SLN(out1 + fcP, z) -> bf16; writes fixed out1 back
    sln_kernel<<<dim3(kB * kL), blk, 0, stream>>>(out1, fcP, out1, z,
                                                  ln2_w, ln2_b, g2, b2, nullptr, h2);
    // 6) hid = gelu(h2 @ mlp1 + b), 8-phase 256^2 (256 blocks = 1/CU exact)
    g8<<<dim3(16, 16, 1), dim3(512), 0, stream>>>(h2, kD, m1T, kD, hid, kHID, kD,
                                                  mlp1_b, nullptr, 3, 0, nullptr, nullptr,
                                                  nullptr, nullptr, nullptr);
    // 7) out0 = hid @ mlp2 + b + out1, 8-phase split-K x4 (256 blocks)
    g8<<<dim3(4, 16, 4), dim3(512), 0, stream>>>(hid, kHID, m2T, kHID, out0, kD, kHID / 4,
                                                 mlp2_b, out1, 0, 4, nullptr, nullptr,
                                                 p1, p2, p3);
    // 8) out0 += p1 + p2 + p3
    combine4<<<dim3(4096), blk, 0, stream>>>(out0, p1, p2, p3);
}

// Round 7
// 753.883 us; speedup vs baseline: 1.1976x; 1.1976x over previous
//
#include <hip/hip_runtime.h>
#include <math.h>

namespace {

constexpr int kL  = 1024;
constexpr int kD  = 1024;
constexpr int kB  = 4;
constexpr int kH  = 16;
constexpr int kDK = 64;
constexpr int kHID = 4096;

typedef unsigned short ushort_t;
typedef short  s16x8 __attribute__((ext_vector_type(8)));   // 8 bf16 (4 VGPRs) MFMA frag
typedef float  f32x4 __attribute__((ext_vector_type(4)));
typedef unsigned short u16x4 __attribute__((ext_vector_type(4)));

// fp32 -> bf16 round-to-nearest-even
__device__ __forceinline__ ushort_t f2bf(float f) {
    unsigned u = __float_as_uint(f);
    unsigned r = u + 0x7fffu + ((u >> 16) & 1u);
    return (ushort_t)(r >> 16);
}

// async global->LDS, 16B per lane. LDS dest = wave-uniform base + lane*16.
__device__ __forceinline__ void gld16(const void* g, void* l) {
    __builtin_amdgcn_global_load_lds((__attribute__((address_space(1))) void*)(g),
                                     (__attribute__((address_space(3))) void*)(l),
                                     16, 0, 0);
}

__device__ __forceinline__ float wred_sum(float v) {
    #pragma unroll
    for (int o = 32; o > 0; o >>= 1) v += __shfl_xor(v, o, 64);
    return v;
}

// ---------------------------------------------------------------------------
// prep: all input-independent prologue work in ONE launch.
// blocks [0,4096):      4x 1024x1024 transpose+cvt (wq,wk,wv,fc) -> wT4
// blocks [4096,8192):   mlp1_w transpose (1024x4096)
// blocks [8192,12288):  mlp2_w transpose (4096x1024)
// blocks [12288,20480): k,v fp32->bf16
// blocks [20480,24576): sln1 rows: qp (fp32) + qb (bf16)
// ---------------------------------------------------------------------------
__global__ __launch_bounds__(256) void prep(
    const float* __restrict__ wq_w, const float* __restrict__ wk_w,
    const float* __restrict__ wv_w, const float* __restrict__ fc_w,
    ushort_t* __restrict__ wT4,
    const float* __restrict__ mlp1_w, ushort_t* __restrict__ m1T,
    const float* __restrict__ mlp2_w, ushort_t* __restrict__ m2T,
    const float* __restrict__ kx, const float* __restrict__ vx, ushort_t* __restrict__ kv,
    const float* __restrict__ q, const float* __restrict__ z,
    const float* __restrict__ ln1w, const float* __restrict__ ln1b,
    const float* __restrict__ g1, const float* __restrict__ b1,
    float* __restrict__ qp, ushort_t* __restrict__ qb)
{
    __shared__ float t[32][33];
    __shared__ float r1[4], r2[4];
    const int b = blockIdx.x;
    const int tid = threadIdx.x;
    if (b < 12288) {
        const float* src; ushort_t* dst; int R, C, bx, by;
        if (b < 4096) {
            int zz = b >> 10, idx = b & 1023;
            src = zz == 0 ? wq_w : zz == 1 ? wk_w : zz == 2 ? wv_w : fc_w;
            dst = wT4 + (size_t)zz * 1048576;
            R = 1024; C = 1024; bx = idx & 31; by = idx >> 5;
        } else if (b < 8192) {
            int idx = b - 4096;
            src = mlp1_w; dst = m1T; R = 1024; C = 4096;
            bx = idx & 127; by = idx >> 7;
        } else {
            int idx = b - 8192;
            src = mlp2_w; dst = m2T; R = 4096; C = 1024;
            bx = idx & 31; by = idx >> 5;
        }
        int c0 = bx * 32, rr0 = by * 32;
        int tx = tid & 31, ty = tid >> 5;
        #pragma unroll
        for (int i = 0; i < 4; i++) {
            int r = ty + i * 8;
            t[r][tx] = src[(size_t)(rr0 + r) * C + c0 + tx];
        }
        __syncthreads();
        #pragma unroll
        for (int i = 0; i < 4; i++) {
            int c = ty + i * 8;
            dst[(size_t)(c0 + c) * R + rr0 + tx] = f2bf(t[tx][c]);
        }
        return;
    }
    if (b < 20480) {
        int bb = b - 12288;
        bool isv = bb >= 4096;
        const float* src = isv ? vx : kx;
        ushort_t* dst = kv + (isv ? (size_t)4194304 : 0);
        int i = (bb & 4095) * 256 + tid;
        f32x4 v = ((const f32x4*)src)[i];
        u16x4 o; o[0] = f2bf(v[0]); o[1] = f2bf(v[1]); o[2] = f2bf(v[2]); o[3] = f2bf(v[3]);
        ((u16x4*)dst)[i] = o;
        return;
    }
    // sln1 row
    {
        const int row = b - 20480;
        const size_t base = (size_t)row * kD;
        float4 xv = ((const float4*)(q + base))[tid];
        float s  = xv.x + xv.y + xv.z + xv.w;
        float sq = xv.x * xv.x + xv.y * xv.y + xv.z * xv.z + xv.w * xv.w;
        float ws = wred_sum(s), wq = wred_sum(sq);
        int lane = tid & 63, wid = tid >> 6;
        if (lane == 0) { r1[wid] = ws; r2[wid] = wq; }
        __syncthreads();
        float st = r1[0] + r1[1] + r1[2] + r1[3];
        float qt = r2[0] + r2[1] + r2[2] + r2[3];
        float mean = st * (1.0f / kD);
        float var  = qt * (1.0f / kD) - mean * mean;
        float rs = rsqrtf(var + 1e-5f);
        float gv = g1[0], bv = b1[0];
        float4 zv = ((const float4*)(z + base))[tid];
        float4 wv = ((const float4*)ln1w)[tid];
        float4 lb = ((const float4*)ln1b)[tid];
        float4 o;
        o.x = zv.x * (gv * ((xv.x - mean) * rs * wv.x + lb.x) + bv);
        o.y = zv.y * (gv * ((xv.y - mean) * rs * wv.y + lb.y) + bv);
        o.z = zv.z * (gv * ((xv.z - mean) * rs * wv.z + lb.z) + bv);
        o.w = zv.w * (gv * ((xv.w - mean) * rs * wv.w + lb.w) + bv);
        ((float4*)(qp + base))[tid] = o;
        u16x4 ob; ob[0] = f2bf(o.x); ob[1] = f2bf(o.y); ob[2] = f2bf(o.z); ob[3] = f2bf(o.w);
        ((u16x4*)(qb + base))[tid] = ob;
    }
}

// out = z * (g * LN(x) + b), where x = x1 (+ x2 partial).
// Optionally writes the summed x back (xw) and the fp32 result (outf).
__global__ __launch_bounds__(256) void sln_kernel(
    const float* __restrict__ x, const float* __restrict__ x2, float* __restrict__ xw,
    const float* __restrict__ z,
    const float* __restrict__ lnw, const float* __restrict__ lnb,
    const float* __restrict__ g, const float* __restrict__ bt,
    float* __restrict__ outf, ushort_t* __restrict__ outb)
{
    const int row = blockIdx.x;
    const int tid = threadIdx.x;
    const size_t base = (size_t)row * kD;
    float4 xv = ((const float4*)(x + base))[tid];
    if (x2) {
        float4 a = ((const float4*)(x2 + base))[tid];
        xv.x += a.x; xv.y += a.y; xv.z += a.z; xv.w += a.w;
    }
    if (xw) ((float4*)(xw + base))[tid] = xv;
    float s  = xv.x + xv.y + xv.z + xv.w;
    float sq = xv.x * xv.x + xv.y * xv.y + xv.z * xv.z + xv.w * xv.w;
    __shared__ float r1[4], r2[4];
    float ws = wred_sum(s), wq = wred_sum(sq);
    int lane = tid & 63, wid = tid >> 6;
    if (lane == 0) { r1[wid] = ws; r2[wid] = wq; }
    __syncthreads();
    float st = r1[0] + r1[1] + r1[2] + r1[3];
    float qt = r2[0] + r2[1] + r2[2] + r2[3];
    float mean = st * (1.0f / kD);
    float var  = qt * (1.0f / kD) - mean * mean;
    float rs = rsqrtf(var + 1e-5f);
    float gv = g[0], bv = bt[0];
    float4 zv = ((const float4*)(z + base))[tid];
    float4 wv = ((const float4*)lnw)[tid];
    float4 lb = ((const float4*)lnb)[tid];
    float4 o;
    o.x = zv.x * (gv * ((xv.x - mean) * rs * wv.x + lb.x) + bv);
    o.y = zv.y * (gv * ((xv.y - mean) * rs * wv.y + lb.y) + bv);
    o.z = zv.z * (gv * ((xv.z - mean) * rs * wv.z + lb.z) + bv);
    o.w = zv.w * (gv * ((xv.w - mean) * rs * wv.w + lb.w) + bv);
    if (outf) ((float4*)(outf + base))[tid] = o;
    u16x4 ob; ob[0] = f2bf(o.x); ob[1] = f2bf(o.y); ob[2] = f2bf(o.z); ob[3] = f2bf(o.w);
    ((u16x4*)(outb + base))[tid] = ob;
}

// dst elementwise += src (fp32, float4 per thread)
__global__ __launch_bounds__(256) void addf4(
    float* __restrict__ dst, const float* __restrict__ src)
{
    int i = blockIdx.x * 256 + threadIdx.x;
    f32x4 d = ((const f32x4*)dst)[i];
    f32x4 s = ((const f32x4*)src)[i];
    d[0] += s[0]; d[1] += s[1]; d[2] += s[2]; d[3] += s[3];
    ((f32x4*)dst)[i] = d;
}

// vh bf16 [b][j][h*64+d] -> vhT bf16 [p=h*4+b][d][j]
__global__ __launch_bounds__(256) void vtrans(
    const ushort_t* __restrict__ vh, ushort_t* __restrict__ vhT)
{
    __shared__ ushort_t t[32][33];
    int p = blockIdx.z, b = p & 3, h = p >> 2;
    int j0 = blockIdx.x * 32, d0 = blockIdx.y * 32;
    int tx = threadIdx.x & 31, ty = threadIdx.x >> 5;
    const ushort_t* src = vh + (size_t)b * (kL * kD) + h * kDK;
    #pragma unroll
    for (int i = 0; i < 4; i++) {
        int j = ty + i * 8;
        t[j][tx] = src[(size_t)(j0 + j) * kD + d0 + tx];
    }
    __syncthreads();
    ushort_t* dst = vhT + (size_t)p * (kDK * kL);
    #pragma unroll
    for (int i = 0; i < 4; i++) {
        int d = ty + i * 8;
        dst[(size_t)(d0 + d) * kL + j0 + tx] = t[tx][d];
    }
}

// MFMA GEMM (m97 structure, BK=64): C = scale*(A @ Bt^T) (+bias)(gelu)(+res).
// A[M][K], Bt[N][K] bf16. 128x128 tile, BK=64 (halved barrier count vs BK=32:
// 32 MFMA per sync; LDS 32KB, still ~3 blocks/CU). 256 thr, 4 waves 64x64.
// Staging: 8 gld16 calls/K-step; thread covers row r0=tid>>3, chunk
// c0=(tid&7)^(r0&7) (XOR swizzle, rows 128B). Read: base ra*128 +
// ((ks*4+q)^(fn&7))*16 — <=2-way bank aliasing (free, m136).
// flags: 1 = gelu, 2 = bf16 output.
// mode 2 = QKV batch: z: A += z*4M elems, Bt += z*1M, C += z*4M (bf16),
//          bias from {bias,bias1,bias2}.
// mode 3 = split-K x2: A/Bt k-offset += z*K; z==1 raw fp32 partial to Cv2.
// XCD-aware bijective swizzle on (bx,by) (nwg%8==0 for all our grids).
__global__ __launch_bounds__(256) void mgemm(
    const ushort_t* __restrict__ A, int lda,
    const ushort_t* __restrict__ Bt, int ldb,
    void* __restrict__ Cv, int ldc, int K,
    const float* __restrict__ bias, const float* __restrict__ res,
    float scale, int flags, int mode,
    const float* __restrict__ bias1, const float* __restrict__ bias2,
    void* __restrict__ Cv2)
{
    __shared__ __align__(16) ushort_t As[128 * 64];   // 16 KB
    __shared__ __align__(16) ushort_t Bs[128 * 64];
    if (mode == 2) {
        int zz = blockIdx.z;
        A  += (size_t)zz * (4096u * 1024u);
        Bt += (size_t)zz * (1024u * 1024u);
        Cv = (void*)((ushort_t*)Cv + (size_t)zz * (4096u * 1024u));
        if (zz == 1) bias = bias1;
        else if (zz == 2) bias = bias2;
    } else if (mode == 3) {
        int zz = blockIdx.z;
        A  += (size_t)zz * K;
        Bt += (size_t)zz * K;
        if (zz == 1) { Cv = Cv2; bias = nullptr; res = nullptr; flags = 0; }
    }
    float*    Cf = (float*)Cv;
    ushort_t* Cb = (ushort_t*)Cv;
    // XCD swizzle (bijective, nwg%8==0)
    const int nx = gridDim.x, nwg = nx * gridDim.y;
    int f = blockIdx.y * nx + blockIdx.x;
    int rr = (f & 7) * (nwg >> 3) + (f >> 3);
    const int bx = rr % nx, by = rr / nx;
    const int tid = threadIdx.x;
    const int lane = tid & 63, w = tid >> 6;
    const int m0 = by * 128, n0 = bx * 128;
    // staging: thread covers row r0 (0..31) + 32*j per call, source chunk c0
    const int r0 = tid >> 3;
    const int c0 = (tid & 7) ^ (r0 & 7);
    const ushort_t* Ag0 = A  + (size_t)(m0 + r0) * lda + c0 * 8;
    const ushort_t* Bg0 = Bt + (size_t)(n0 + r0) * ldb + c0 * 8;
    char* AsW = (char*)As + w * 1024;   // wave-uniform LDS dest (call j: +j*4096)
    char* BsW = (char*)Bs + w * 1024;
    const int wm = (w & 1) * 64, wn = (w >> 1) * 64;
    const int fn = lane & 15, q = lane >> 4;
    // fragment bases: row ra at byte ra*128; k-chunk (ks*4+q) xor'd by fn&7
    int abase[4], bbase[4], xoff[2];
    #pragma unroll
    for (int i = 0; i < 4; i++) {
        abase[i] = (wm + i * 16 + fn) * 128;
        bbase[i] = (wn + i * 16 + fn) * 128;
    }
    #pragma unroll
    for (int ks = 0; ks < 2; ks++) xoff[ks] = ((ks * 4 + q) ^ (fn & 7)) << 4;
    f32x4 acc[4][4] = {};
    for (int k0 = 0; k0 < K; k0 += 64) {
        gld16(Ag0 + k0, AsW);
        gld16(Ag0 + (size_t)32 * lda + k0, AsW + 4096);
        gld16(Ag0 + (size_t)64 * lda + k0, AsW + 8192);
        gld16(Ag0 + (size_t)96 * lda + k0, AsW + 12288);
        gld16(Bg0 + k0, BsW);
        gld16(Bg0 + (size_t)32 * ldb + k0, BsW + 4096);
        gld16(Bg0 + (size_t)64 * ldb + k0, BsW + 8192);
        gld16(Bg0 + (size_t)96 * ldb + k0, BsW + 12288);
        __syncthreads();
        #pragma unroll
        for (int ks = 0; ks < 2; ks++) {
            s16x8 af[4], bfr[4];
            #pragma unroll
            for (int i = 0; i < 4; i++) {
                af[i]  = *(const s16x8*)((const char*)As + abase[i] + xoff[ks]);
                bfr[i] = *(const s16x8*)((const char*)Bs + bbase[i] + xoff[ks]);
            }
            #pragma unroll
            for (int mi = 0; mi < 4; mi++)
                #pragma unroll
                for (int ni = 0; ni < 4; ni++)
                    acc[mi][ni] = __builtin_amdgcn_mfma_f32_16x16x32_bf16(
                        af[mi], bfr[ni], acc[mi][ni], 0, 0, 0);
        }
        __syncthreads();
    }
    #pragma unroll
    for (int mi = 0; mi < 4; mi++) {
        #pragma unroll
        for (int ni = 0; ni < 4; ni++) {
            #pragma unroll
            for (int r = 0; r < 4; r++) {
                int gm = m0 + wm + mi * 16 + q * 4 + r;   // C/D row = quad*4+reg
                int gn = n0 + wn + ni * 16 + fn;          // C/D col = lane&15
                float v = acc[mi][ni][r] * scale;
                if (bias) v += bias[gn];
                if (flags & 1) v = 0.5f * v * (1.0f + erff(v * 0.70710678118654752f));
                if (res) v += res[(size_t)gm * ldc + gn];
                if (flags & 2) Cb[(size_t)gm * ldc + gn] = f2bf(v);
                else           Cf[(size_t)gm * ldc + gn] = v;
            }
        }
    }
}

// Fused attention: per block = one (b,h) pair p and a 32-row Q-tile.
// Phase 1: S = (Q @ K^T)/8; block row softmax; write normalized P (fp32, nt).
// Phase 2: E (bf16) via per-wave XOR-swizzled LDS transpose; ctx = (E@V)*inv;
// cross-wave reduce in LDS. XCD-bijective block swizzle for K/V L2 residency.
__global__ __launch_bounds__(512) void fused_attn(
    const ushort_t* __restrict__ qh, const ushort_t* __restrict__ kh,
    const ushort_t* __restrict__ vhT, float* __restrict__ attn,
    ushort_t* __restrict__ ctx)
{
    __shared__ __align__(16) char PlBuf[8 * 4096];   // per-wave E tiles / cred overlay
    __shared__ float redm[8][32];
    __shared__ float reds[8][32];
    const int orig = blockIdx.y * 32 + blockIdx.x;   // grid (32, 64), 2048 blocks
    const int nf = (orig & 7) * 256 + (orig >> 3);
    const int p = nf >> 5, b = p & 3, h = p >> 2;
    const int m0 = (nf & 31) * 32;
    const int tid = threadIdx.x;
    const int lane = tid & 63, w = tid >> 6;
    const int fn = lane & 15, q = lane >> 4;
    const ushort_t* Qb = qh + (size_t)b * (kL * kD) + h * 64;
    const ushort_t* Kb = kh + (size_t)b * (kL * kD) + h * 64;
    float* Pp = attn + (size_t)p * kL * kL;

    // ---- Phase 1: S = Q K^T * 1/8 ----
    f32x4 acc[2][8] = {};
    #pragma unroll
    for (int kk = 0; kk < 2; kk++) {
        s16x8 aq[2], bq[8];
        #pragma unroll
        for (int mi = 0; mi < 2; mi++)
            aq[mi] = *(const s16x8*)(Qb + (size_t)(m0 + mi * 16 + fn) * kD + kk * 32 + q * 8);
        #pragma unroll
        for (int ni = 0; ni < 8; ni++)
            bq[ni] = *(const s16x8*)(Kb + (size_t)(w * 128 + ni * 16 + fn) * kD + kk * 32 + q * 8);
        #pragma unroll
        for (int mi = 0; mi < 2; mi++)
            #pragma unroll
            for (int ni = 0; ni < 8; ni++)
                acc[mi][ni] = __builtin_amdgcn_mfma_f32_16x16x32_bf16(
                    aq[mi], bq[ni], acc[mi][ni], 0, 0, 0);
    }

    // ---- softmax ----
    float mloc[2][4];
    #pragma unroll
    for (int mi = 0; mi < 2; mi++) {
        #pragma unroll
        for (int r = 0; r < 4; r++) {
            float m = -3.0e38f;
            #pragma unroll
            for (int ni = 0; ni < 8; ni++) {
                acc[mi][ni][r] *= 0.125f;
                m = fmaxf(m, acc[mi][ni][r]);
            }
            mloc[mi][r] = m;
        }
    }
    #pragma unroll
    for (int o = 1; o < 16; o <<= 1) {
        #pragma unroll
        for (int mi = 0; mi < 2; mi++)
            #pragma unroll
            for (int r = 0; r < 4; r++)
                mloc[mi][r] = fmaxf(mloc[mi][r], __shfl_xor(mloc[mi][r], o, 64));
    }
    if (fn == 0) {
        #pragma unroll
        for (int mi = 0; mi < 2; mi++)
            #pragma unroll
            for (int r = 0; r < 4; r++)
                redm[w][mi * 16 + q * 4 + r] = mloc[mi][r];
    }
    __syncthreads();
    #pragma unroll
    for (int mi = 0; mi < 2; mi++) {
        #pragma unroll
        for (int r = 0; r < 4; r++) {
            int row = mi * 16 + q * 4 + r;
            float m = redm[0][row];
            #pragma unroll
            for (int w2 = 1; w2 < 8; w2++) m = fmaxf(m, redm[w2][row]);
            float s = 0.f;
            #pragma unroll
            for (int ni = 0; ni < 8; ni++) {
                float e = __expf(acc[mi][ni][r] - m);
                acc[mi][ni][r] = e;
                s += e;
            }
            mloc[mi][r] = s;
        }
    }
    #pragma unroll
    for (int o = 1; o < 16; o <<= 1) {
        #pragma unroll
        for (int mi = 0; mi < 2; mi++)
            #pragma unroll
            for (int r = 0; r < 4; r++)
                mloc[mi][r] += __shfl_xor(mloc[mi][r], o, 64);
    }
    if (fn == 0) {
        #pragma unroll
        for (int mi = 0; mi < 2; mi++)
            #pragma unroll
            for (int r = 0; r < 4; r++)
                reds[w][mi * 16 + q * 4 + r] = mloc[mi][r];
    }
    __syncthreads();
    float inv[2][4];
    #pragma unroll
    for (int mi = 0; mi < 2; mi++) {
        #pragma unroll
        for (int r = 0; r < 4; r++) {
            int row = mi * 16 + q * 4 + r;
            float s = reds[0][row];
            #pragma unroll
            for (int w2 = 1; w2 < 8; w2++) s += reds[w2][row];
            inv[mi][r] = 1.0f / s;
        }
    }
    // ---- write normalized P (required output), nontemporal ----
    #pragma unroll
    for (int mi = 0; mi < 2; mi++)
        #pragma unroll
        for (int ni = 0; ni < 8; ni++)
            #pragma unroll
            for (int r = 0; r < 4; r++)
                __builtin_nontemporal_store(
                    acc[mi][ni][r] * inv[mi][r],
                    &Pp[(size_t)(m0 + mi * 16 + q * 4 + r) * kL + w * 128 + ni * 16 + fn]);

    // ---- Phase 2: ctx_partial = (E @ V) * inv via per-wave LDS transpose ----
    const ushort_t* Vb = vhT + (size_t)p * (kDK * kL);
    char* Plw = PlBuf + w * 4096;
    f32x4 acc2[2][4] = {};
    #pragma unroll
    for (int half = 0; half < 2; half++) {
        #pragma unroll
        for (int mi = 0; mi < 2; mi++)
            #pragma unroll
            for (int ni = 0; ni < 4; ni++)
                #pragma unroll
                for (int r = 0; r < 4; r++) {
                    int row = mi * 16 + q * 4 + r;
                    int cl  = ni * 16 + fn;
                    *(ushort_t*)(Plw + ((row * 128 + cl * 2) ^ ((row & 7) << 4)))
                        = f2bf(acc[mi][half * 4 + ni][r]);
                }
        #pragma unroll
        for (int kh2 = 0; kh2 < 2; kh2++) {
            int kk = half * 2 + kh2;
            s16x8 pa[2];
            #pragma unroll
            for (int mi = 0; mi < 2; mi++) {
                int row = mi * 16 + fn;
                pa[mi] = *(const s16x8*)(Plw +
                    ((row * 128 + (kh2 * 32 + q * 8) * 2) ^ ((row & 7) << 4)));
            }
            #pragma unroll
            for (int nj = 0; nj < 4; nj++) {
                s16x8 bv = *(const s16x8*)(Vb + (size_t)(nj * 16 + fn) * kL +
                                           w * 128 + kk * 32 + q * 8);
                #pragma unroll
                for (int mi = 0; mi < 2; mi++)
                    acc2[mi][nj] = __builtin_amdgcn_mfma_f32_16x16x32_bf16(
                        pa[mi], bv, acc2[mi][nj], 0, 0, 0);
            }
        }
    }
    #pragma unroll
    for (int mi = 0; mi < 2; mi++)
        #pragma unroll
        for (int nj = 0; nj < 4; nj++)
            #pragma unroll
            for (int r = 0; r < 4; r++)
                acc2[mi][nj][r] *= inv[mi][r];

    // ---- cross-wave reduce (8 -> 4 -> 1); cred overlays PlBuf ----
    __syncthreads();
    float (*cred)[2048] = (float (*)[2048])PlBuf;
    if (w < 4) {
        #pragma unroll
        for (int mi = 0; mi < 2; mi++)
            #pragma unroll
            for (int nj = 0; nj < 4; nj++)
                #pragma unroll
                for (int r = 0; r < 4; r++)
                    cred[w][(mi * 16 + q * 4 + r) * 64 + nj * 16 + fn] = acc2[mi][nj][r];
    }
    __syncthreads();
    if (w >= 4) {
        #pragma unroll
        for (int mi = 0; mi < 2; mi++)
            #pragma unroll
            for (int nj = 0; nj < 4; nj++)
                #pragma unroll
                for (int r = 0; r < 4; r++)
                    cred[w - 4][(mi * 16 + q * 4 + r) * 64 + nj * 16 + fn] += acc2[mi][nj][r];
    }
    __syncthreads();
    {
        int idx0 = tid * 4;
        int row = idx0 >> 6, d0 = idx0 & 63;
        f32x4 s0 = *(const f32x4*)&cred[0][idx0];
        #pragma unroll
        for (int wb = 1; wb < 4; wb++) {
            f32x4 t = *(const f32x4*)&cred[wb][idx0];
            s0[0] += t[0]; s0[1] += t[1]; s0[2] += t[2]; s0[3] += t[3];
        }
        u16x4 o;
        o[0] = f2bf(s0[0]); o[1] = f2bf(s0[1]); o[2] = f2bf(s0[2]); o[3] = f2bf(s0[3]);
        *(u16x4*)(ctx + (size_t)b * (kL * kD) + (size_t)(m0 + row) * kD + h * 64 + d0) = o;
    }
}

} // namespace

extern "C" void kernel_launch(void* const* d_in, const int* in_sizes, int n_in,
                              void* d_out, int out_size, void* d_ws, size_t ws_size,
                              hipStream_t stream)
{
    (void)in_sizes; (void)n_in; (void)out_size; (void)ws_size;
    const float* q      = (const float*)d_in[0];
    const float* k      = (const float*)d_in[1];
    const float* v      = (const float*)d_in[2];
    const float* z      = (const float*)d_in[3];
    const float* wq_w   = (const float*)d_in[4];
    const float* wq_b   = (const float*)d_in[5];
    const float* wk_w   = (const float*)d_in[6];
    const float* wk_b   = (const float*)d_in[7];
    const float* wv_w   = (const float*)d_in[8];
    const float* wv_b   = (const float*)d_in[9];
    const float* fc_w   = (const float*)d_in[10];
    const float* fc_b   = (const float*)d_in[11];
    const float* mlp1_w = (const float*)d_in[12];
    const float* mlp1_b = (const float*)d_in[13];
    const float* mlp2_w = (const float*)d_in[14];
    const float* mlp2_b = (const float*)d_in[15];
    const float* ln1_w  = (const float*)d_in[16];
    const float* ln1_b  = (const float*)d_in[17];
    const float* g1     = (const float*)d_in[18];
    const float* b1     = (const float*)d_in[19];
    const float* ln2_w  = (const float*)d_in[20];
    const float* ln2_b  = (const float*)d_in[21];
    const float* g2     = (const float*)d_in[22];
    const float* b2     = (const float*)d_in[23];

    float* out0 = (float*)d_out;                          // (B,L,D)
    float* attn = (float*)d_out + (size_t)kB * kL * kD;   // (H*B,L,L)

    // workspace arena (104 MB peak, lifetime-overlay layout) — R3 layout
    char* arena = (char*)d_ws;
    const size_t MB = 1u << 20;
    float*    qp   = (float*)(arena);
    ushort_t* qb   = (ushort_t*)(arena + 16 * MB);
    ushort_t* kb   = (ushort_t*)(arena + 24 * MB);
    ushort_t* vb   = (ushort_t*)(arena + 32 * MB);
    ushort_t* qh   = (ushort_t*)(arena + 40 * MB);
    ushort_t* kh   = (ushort_t*)(arena + 48 * MB);
    ushort_t* vh   = (ushort_t*)(arena + 56 * MB);
    ushort_t* vhT  = (ushort_t*)(arena + 32 * MB);     // overlays vb (dead)
    ushort_t* ctx  = (ushort_t*)(arena + 56 * MB);     // overlays vh (dead)
    float*    fcP  = (float*)(arena + 16 * MB);        // overlays qb,kb (dead)
    ushort_t* h2   = (ushort_t*)(arena + 32 * MB);     // overlays vhT (dead)
    float*    out1 = (float*)(arena + 64 * MB);
    ushort_t* hid  = (ushort_t*)(arena);               // [0,32) overlays qp,fcP (dead)
    float*    m2P  = (float*)(arena + 40 * MB);        // overlays qh,kh (dead)
    ushort_t* wT4  = (ushort_t*)(arena + 80 * MB);
    ushort_t* fcT  = (ushort_t*)(arena + 86 * MB);
    ushort_t* m1T  = (ushort_t*)(arena + 88 * MB);
    ushort_t* m2T  = (ushort_t*)(arena + 96 * MB);

    dim3 blk(256);
    // 0) all prologue work in one launch (transposes, k/v cvt, sln1)
    prep<<<dim3(24576), blk, 0, stream>>>(wq_w, wk_w, wv_w, fc_w, wT4,
                                          mlp1_w, m1T, mlp2_w, m2T,
                                          k, v, kb,
                                          q, z, ln1_w, ln1_b, g1, b1, qp, qb);
    // 1) QKV projections -> bf16 heads, batched (768 blocks = 3/CU)
    mgemm<<<dim3(8, 32, 3), blk, 0, stream>>>(qb, kD, wT4, kD, qh, kD, kD,
                                              wq_b, nullptr, 1.0f, 2, 2, wk_b, wv_b, nullptr);
    // 2) V^T per head
    vtrans<<<dim3(32, 2, 64), blk, 0, stream>>>(vh, vhT);
    // 3) fused scores+softmax+PV: attn (fp32, d_out) and ctx (bf16)
    fused_attn<<<dim3(kL / 32, 64), dim3(512), 0, stream>>>(qh, kh, vhT, attn, ctx);
    // 4) out1 = ctx @ fc_w + fc_b + q', split-K x2 (512 blocks = 2/CU):
    //    z=0 -> out1 (K 0..511, bias+res), z=1 -> fcP raw partial (K 512..1023)
    mgemm<<<dim3(8, 32, 2), blk, 0, stream>>>(ctx, kD, fcT, kD, out1, kD, kD / 2,
                                              fc_b, qp, 1.0f, 0, 3, nullptr, nullptr, fcP);
    // 5) h2 = SLN(out1 + fcP, z) -> bf16; writes fixed out1 back (residual for 7)
    sln_kernel<<<dim3(kB * kL), blk, 0, stream>>>(out1, fcP, out1, z,
                                                  ln2_w, ln2_b, g2, b2, nullptr, h2);
    // 6) hid = gelu(h2 @ mlp1 + b) -> bf16 (1024 blocks = 4/CU)
    mgemm<<<dim3(32, 32, 1), blk, 0, stream>>>(h2, kD, m1T, kD, hid, kHID, kD,
                                               mlp1_b, nullptr, 1.0f, 3, 0, nullptr, nullptr, nullptr);
    // 7) out0 = hid @ mlp2 + b + out1, split-K x2 (512 blocks = 2/CU):
    //    z=0 -> out0 (K 0..2047, bias+res), z=1 -> m2P raw partial
    mgemm<<<dim3(8, 32, 2), blk, 0, stream>>>(hid, kHID, m2T, kHID, out0, kD, kHID / 2,
                                              mlp2_b, out1, 1.0f, 0, 3, nullptr, nullptr, m2P);
    // 8) out0 += m2P
    addf4<<<dim3(4096), blk, 0, stream>>>(out0, m2P);
}